// Round 4
// baseline (186.474 us; speedup 1.0000x reference)
//
#include <hip/hip_runtime.h>
#include <cstdint>

// Problem constants: B=32, C=256, P=32, H=W=56
#define B_   32
#define C_   256
#define P_   32
#define HW_  3136
#define KT   64           // K per block-round (2 MFMA k-steps)
#define NT64 49           // HW_/KT
#define KSPLIT_MAX 49     // one round per block when ws allows

typedef __attribute__((ext_vector_type(8))) short  short8;   // 8 x bf16 (MFMA A/B frag)
typedef __attribute__((ext_vector_type(4))) float  floatx4;  // MFMA C/D frag

__device__ __forceinline__ unsigned short f2bf(float f) {
    // round-to-nearest-even f32 -> bf16
    union { float f; unsigned u; } v; v.f = f;
    unsigned r = v.u + 0x7fffu + ((v.u >> 16) & 1u);
    return (unsigned short)(r >> 16);
}

// ---------------------------------------------------------------------------
// Kernel 1: att[b,hw] = sigmoid( sum_p part[b,p,hw]*conv_w[p] + conv_b )
// ---------------------------------------------------------------------------
__global__ __launch_bounds__(64) void att_kernel(
    const float* __restrict__ part, const float* __restrict__ conv_w,
    const float* __restrict__ conv_b, float* __restrict__ att)
{
    const int HW4 = HW_ / 4;                          // 784
    int i4 = blockIdx.x * 64 + threadIdx.x;           // over B*HW/4 = 25088
    if (i4 >= B_ * HW4) return;
    int b  = i4 / HW4;
    int hw = (i4 - b * HW4) * 4;

    const float* pb = part + (size_t)b * P_ * HW_ + hw;
    float bias = conv_b[0];
    float4 z = make_float4(bias, bias, bias, bias);
#pragma unroll
    for (int p = 0; p < P_; ++p) {
        float w = conv_w[p];
        float4 v = *(const float4*)(pb + (size_t)p * HW_);
        z.x += v.x * w; z.y += v.y * w; z.z += v.z * w; z.w += v.w * w;
    }
    float4 s;
    s.x = 1.0f / (1.0f + __expf(-z.x));
    s.y = 1.0f / (1.0f + __expf(-z.y));
    s.z = 1.0f / (1.0f + __expf(-z.z));
    s.w = 1.0f / (1.0f + __expf(-z.w));
    *(float4*)(att + (size_t)b * HW_ + hw) = s;
}

// ---------------------------------------------------------------------------
// Kernel 2: streaming one-round batched bf16-MFMA GEMM.
//   feats[b,p,c] = sum_k (part[b,p,k]*att[b,k]) * x[b,c,k]
// att folded into the SMALL A operand (32 rows) -> B staging is pure cvt.
// Block: 256 thr (4 waves), tile M=32 x N=128 (ch half) x KT=64, normally
// exactly ONE round (ksplit=49) -> stage, 1 barrier, 8 MFMA, store, exit.
// ~4 blocks/CU, block churn keeps loads continuously in flight (streaming).
// ---------------------------------------------------------------------------
__global__ __launch_bounds__(256, 4) void gemm_onepass(
    const float* __restrict__ x,        // [B,C,HW]
    const float* __restrict__ part,     // [B,P,HW]
    const float* __restrict__ att,      // [B,HW]
    float* __restrict__ partial,        // [ksplit, B, P, C]
    int ksplit)
{
    __shared__ __align__(16) unsigned short Abf[P_][KT + 8];    // 32 x 72 =  4,608 B
    __shared__ __align__(16) unsigned short Bbf[128][KT + 8];   // 128x 72 = 18,432 B

    const int kc = blockIdx.x;
    const int b  = blockIdx.y;
    const int ch = blockIdx.z;          // c half: [ch*128, ch*128+128)
    const int t0 = kc * NT64 / ksplit;
    const int t1 = (kc + 1) * NT64 / ksplit;

    const int tid  = threadIdx.x;
    const int lane = tid & 63;
    const int wv   = tid >> 6;          // wave 0..3 -> c_local range [wv*32, +32)
    const int qd   = lane >> 4;         // quad 0..3
    const int r15  = lane & 15;

    // staging map: 16 k-phases x 16 rows
    const int sr = tid >> 4;            // 0..15
    const int k4 = (tid & 15) << 2;     // 0,4,...,60

    const float* xb = x    + (size_t)b * C_ * HW_ + (size_t)(ch * 128) * HW_ + k4;
    const float* pb = part + (size_t)b * P_ * HW_ + k4;
    const float* ab = att  + (size_t)b * HW_ + k4;

    floatx4 acc[2][2];
#pragma unroll
    for (int mt = 0; mt < 2; ++mt)
#pragma unroll
        for (int nt = 0; nt < 2; ++nt) acc[mt][nt] = (floatx4)0.0f;

    for (int t = t0; t < t1; ++t) {
        const int kb = t * KT;

        // ---- global loads: A rows sr, sr+16 ; att ; 8 x-rows ----
        float4 pv0 = *(const float4*)(pb + (size_t)sr * HW_ + kb);
        float4 pv1 = *(const float4*)(pb + (size_t)(sr + 16) * HW_ + kb);
        float4 av  = *(const float4*)(ab + kb);
        float4 xv[8];
#pragma unroll
        for (int l = 0; l < 8; ++l)
            xv[l] = *(const float4*)(xb + (size_t)((l << 4) + sr) * HW_ + kb);

        // ---- stage A = bf16(part * att) ----
        {
            ushort4 a4;
            a4.x = f2bf(pv0.x * av.x); a4.y = f2bf(pv0.y * av.y);
            a4.z = f2bf(pv0.z * av.z); a4.w = f2bf(pv0.w * av.w);
            *(ushort4*)&Abf[sr][k4] = a4;
            a4.x = f2bf(pv1.x * av.x); a4.y = f2bf(pv1.y * av.y);
            a4.z = f2bf(pv1.z * av.z); a4.w = f2bf(pv1.w * av.w);
            *(ushort4*)&Abf[sr + 16][k4] = a4;
        }
        // ---- stage B = bf16(x)  (no att here) ----
#pragma unroll
        for (int l = 0; l < 8; ++l) {
            ushort4 b4;
            b4.x = f2bf(xv[l].x); b4.y = f2bf(xv[l].y);
            b4.z = f2bf(xv[l].z); b4.w = f2bf(xv[l].w);
            *(ushort4*)&Bbf[(l << 4) + sr][k4] = b4;
        }
        __syncthreads();   // tile ready

        // ---- MFMA: 2 k-steps x (2 mt x 2 nt), wave covers c_local [wv*32,+32) ----
#pragma unroll
        for (int ks = 0; ks < 2; ++ks) {
            const int ko = ks * 32 + qd * 8;
            short8 af0 = *(const short8*)&Abf[r15][ko];
            short8 af1 = *(const short8*)&Abf[16 + r15][ko];
            short8 bf0 = *(const short8*)&Bbf[(wv << 5) + r15][ko];
            short8 bf1 = *(const short8*)&Bbf[(wv << 5) + 16 + r15][ko];
            acc[0][0] = __builtin_amdgcn_mfma_f32_16x16x32_bf16(af0, bf0, acc[0][0], 0, 0, 0);
            acc[0][1] = __builtin_amdgcn_mfma_f32_16x16x32_bf16(af0, bf1, acc[0][1], 0, 0, 0);
            acc[1][0] = __builtin_amdgcn_mfma_f32_16x16x32_bf16(af1, bf0, acc[1][0], 0, 0, 0);
            acc[1][1] = __builtin_amdgcn_mfma_f32_16x16x32_bf16(af1, bf1, acc[1][1], 0, 0, 0);
        }
        if (t + 1 < t1) __syncthreads();   // only if looping (ksplit < 49)
    }

    // ---- epilogue: plain stores of K-split partials ----
    // D layout: row(m=p) = qd*4 + reg, col(n) = r15
    float* ob = partial + ((size_t)kc * B_ + b) * (P_ * C_);
#pragma unroll
    for (int mt = 0; mt < 2; ++mt) {
#pragma unroll
        for (int nt = 0; nt < 2; ++nt) {
#pragma unroll
            for (int rg = 0; rg < 4; ++rg) {
                int p = mt * 16 + qd * 4 + rg;
                int c = ch * 128 + (wv << 5) + nt * 16 + r15;
                ob[p * C_ + c] = acc[mt][nt][rg];
            }
        }
    }
}

// ---------------------------------------------------------------------------
// Kernel 3: out[i] = sum_kc partial[kc][i].  float4 over 262144 floats.
// Partials were just written -> mostly L3-resident.
// ---------------------------------------------------------------------------
__global__ __launch_bounds__(256) void reduce_k(
    const float* __restrict__ partial, float* __restrict__ out, int ksplit)
{
    int i = blockIdx.x * 256 + threadIdx.x;       // over 65536 float4s
    const float4* p4 = (const float4*)partial;
    float4 s = p4[i];
    for (int kc = 1; kc < ksplit; ++kc) {
        float4 v = p4[(size_t)kc * (B_ * P_ * C_ / 4) + i];
        s.x += v.x; s.y += v.y; s.z += v.z; s.w += v.w;
    }
    ((float4*)out)[i] = s;
}

extern "C" void kernel_launch(void* const* d_in, const int* in_sizes, int n_in,
                              void* d_out, int out_size, void* d_ws, size_t ws_size,
                              hipStream_t stream) {
    const float* x      = (const float*)d_in[0];
    const float* part   = (const float*)d_in[1];
    const float* conv_w = (const float*)d_in[2];
    const float* conv_b = (const float*)d_in[3];

    // ws layout: [0, 2MB) att ; [2MB, ...) K-split partials (1 MiB per split)
    const size_t ATT_OFF = 2u << 20;
    float* att = (float*)d_ws;
    const size_t slab = (size_t)B_ * P_ * C_ * 4;
    int ksplit = (ws_size > ATT_OFF) ? (int)((ws_size - ATT_OFF) / slab) : 1;
    if (ksplit > KSPLIT_MAX) ksplit = KSPLIT_MAX;
    if (ksplit < 1) ksplit = 1;
    float* partial = (ksplit > 1) ? (float*)((char*)d_ws + ATT_OFF) : (float*)d_out;

    att_kernel<<<dim3((B_ * (HW_ / 4) + 63) / 64), dim3(64), 0, stream>>>(
        part, conv_w, conv_b, att);

    gemm_onepass<<<dim3(ksplit, B_, 2), dim3(256), 0, stream>>>(
        x, part, att, partial, ksplit);

    if (ksplit > 1) {
        reduce_k<<<dim3((B_ * P_ * C_ / 4) / 256), dim3(256), 0, stream>>>(
            partial, (float*)d_out, ksplit);
    }
}

// Round 5
// 186.254 us; speedup vs baseline: 1.0012x; 1.0012x over previous
//
#include <hip/hip_runtime.h>
#include <cstdint>

// Problem constants: B=32, C=256, P=32, H=W=56
#define B_   32
#define C_   256
#define P_   32
#define HW_  3136
#define KT   64           // K per round (2 MFMA k-steps)
#define NT64 49           // HW_/KT
#define KSPLIT 16

typedef __attribute__((ext_vector_type(8))) short  short8;   // 8 x bf16 (MFMA A/B frag)
typedef __attribute__((ext_vector_type(4))) float  floatx4;  // MFMA C/D frag

__device__ __forceinline__ unsigned short f2bf(float f) {
    // round-to-nearest-even f32 -> bf16
    union { float f; unsigned u; } v; v.f = f;
    unsigned r = v.u + 0x7fffu + ((v.u >> 16) & 1u);
    return (unsigned short)(r >> 16);
}

// ---------------------------------------------------------------------------
// Kernel 1: att[b,hw] = sigmoid( sum_p part[b,p,hw]*conv_w[p] + conv_b )
// ~3 us, proven.
// ---------------------------------------------------------------------------
__global__ __launch_bounds__(64) void att_kernel(
    const float* __restrict__ part, const float* __restrict__ conv_w,
    const float* __restrict__ conv_b, float* __restrict__ att)
{
    const int HW4 = HW_ / 4;                          // 784
    int i4 = blockIdx.x * 64 + threadIdx.x;           // over B*HW/4 = 25088
    if (i4 >= B_ * HW4) return;
    int b  = i4 / HW4;
    int hw = (i4 - b * HW4) * 4;

    const float* pb = part + (size_t)b * P_ * HW_ + hw;
    float bias = conv_b[0];
    float4 z = make_float4(bias, bias, bias, bias);
#pragma unroll
    for (int p = 0; p < P_; ++p) {
        float w = conv_w[p];
        float4 v = *(const float4*)(pb + (size_t)p * HW_);
        z.x += v.x * w; z.y += v.y * w; z.z += v.z * w; z.w += v.w * w;
    }
    float4 s;
    s.x = 1.0f / (1.0f + __expf(-z.x));
    s.y = 1.0f / (1.0f + __expf(-z.y));
    s.z = 1.0f / (1.0f + __expf(-z.z));
    s.w = 1.0f / (1.0f + __expf(-z.w));
    *(float4*)(att + (size_t)b * HW_ + hw) = s;
}

// ---------------------------------------------------------------------------
// Kernel 2: batched bf16-MFMA GEMM, K-split accumulated via atomicAdd into
// zeroed d_out (NO partials round-trip, NO reduce kernel).
//   feats[b,p,c] = sum_k (part[b,p,k]*att[b,k]) * x[b,c,k]
// Grid (KSPLIT=16, B=32, ch=2) = 1024 blocks, 256 thr, 3-4 rounds each,
// one barrier per round. Tile M=32 x N=128 x KT=64.  LDS 23 KB -> 4 blk/CU.
// Epilogue: 16 adds/word total across grid; per-wave line-coalesced bursts,
// store order rotated by kc so racing blocks start on different lines.
// ---------------------------------------------------------------------------
__global__ __launch_bounds__(256, 4) void gemm_atomic(
    const float* __restrict__ x,        // [B,C,HW]
    const float* __restrict__ part,     // [B,P,HW]
    const float* __restrict__ att,      // [B,HW]
    float* __restrict__ out)            // [B, P*C], pre-zeroed
{
    __shared__ __align__(16) unsigned short Abf[P_][KT + 8];    // 32 x 72 =  4,608 B
    __shared__ __align__(16) unsigned short Bbf[128][KT + 8];   // 128x 72 = 18,432 B

    const int kc = blockIdx.x;
    const int b  = blockIdx.y;
    const int ch = blockIdx.z;          // c half: [ch*128, ch*128+128)
    const int t0 = kc * NT64 / KSPLIT;
    const int t1 = (kc + 1) * NT64 / KSPLIT;

    const int tid  = threadIdx.x;
    const int lane = tid & 63;
    const int wv   = tid >> 6;          // wave 0..3 -> c_local range [wv*32, +32)
    const int qd   = lane >> 4;         // quad 0..3
    const int r15  = lane & 15;

    // staging map: 16 k-phases x 16 rows (one 256B txn per 16-lane group)
    const int sr = tid >> 4;            // 0..15
    const int k4 = (tid & 15) << 2;     // 0,4,...,60

    const float* xb = x    + (size_t)b * C_ * HW_ + (size_t)(ch * 128) * HW_ + k4;
    const float* pb = part + (size_t)b * P_ * HW_ + k4;
    const float* ab = att  + (size_t)b * HW_ + k4;

    floatx4 acc[2][2];
#pragma unroll
    for (int mt = 0; mt < 2; ++mt)
#pragma unroll
        for (int nt = 0; nt < 2; ++nt) acc[mt][nt] = (floatx4)0.0f;

    for (int t = t0; t < t1; ++t) {
        const int kb = t * KT;

        // ---- global loads for this round ----
        float4 pv0 = *(const float4*)(pb + (size_t)sr * HW_ + kb);
        float4 pv1 = *(const float4*)(pb + (size_t)(sr + 16) * HW_ + kb);
        float4 av  = *(const float4*)(ab + kb);
        float4 xv[8];
#pragma unroll
        for (int l = 0; l < 8; ++l)
            xv[l] = *(const float4*)(xb + (size_t)((l << 4) + sr) * HW_ + kb);

        // ---- stage A = bf16(part * att) (att folded into the small operand) ----
        {
            ushort4 a4;
            a4.x = f2bf(pv0.x * av.x); a4.y = f2bf(pv0.y * av.y);
            a4.z = f2bf(pv0.z * av.z); a4.w = f2bf(pv0.w * av.w);
            *(ushort4*)&Abf[sr][k4] = a4;
            a4.x = f2bf(pv1.x * av.x); a4.y = f2bf(pv1.y * av.y);
            a4.z = f2bf(pv1.z * av.z); a4.w = f2bf(pv1.w * av.w);
            *(ushort4*)&Abf[sr + 16][k4] = a4;
        }
        // ---- stage B = bf16(x) ----
#pragma unroll
        for (int l = 0; l < 8; ++l) {
            ushort4 b4;
            b4.x = f2bf(xv[l].x); b4.y = f2bf(xv[l].y);
            b4.z = f2bf(xv[l].z); b4.w = f2bf(xv[l].w);
            *(ushort4*)&Bbf[(l << 4) + sr][k4] = b4;
        }
        __syncthreads();   // tile ready

        // ---- MFMA: 2 k-steps x (2 mt x 2 nt) ----
#pragma unroll
        for (int ks = 0; ks < 2; ++ks) {
            const int ko = ks * 32 + qd * 8;
            short8 af0 = *(const short8*)&Abf[r15][ko];
            short8 af1 = *(const short8*)&Abf[16 + r15][ko];
            short8 bf0 = *(const short8*)&Bbf[(wv << 5) + r15][ko];
            short8 bf1 = *(const short8*)&Bbf[(wv << 5) + 16 + r15][ko];
            acc[0][0] = __builtin_amdgcn_mfma_f32_16x16x32_bf16(af0, bf0, acc[0][0], 0, 0, 0);
            acc[0][1] = __builtin_amdgcn_mfma_f32_16x16x32_bf16(af0, bf1, acc[0][1], 0, 0, 0);
            acc[1][0] = __builtin_amdgcn_mfma_f32_16x16x32_bf16(af1, bf0, acc[1][0], 0, 0, 0);
            acc[1][1] = __builtin_amdgcn_mfma_f32_16x16x32_bf16(af1, bf1, acc[1][1], 0, 0, 0);
        }
        if (t + 1 < t1) __syncthreads();   // skip the trailing barrier on the last round
    }

    // ---- epilogue: atomic accumulate into d_out, kc-rotated store order ----
    // D layout: row(m=p) = qd*4 + reg, col(n) = r15
    float* ob = out + (size_t)b * (P_ * C_);
#pragma unroll
    for (int mt = 0; mt < 2; ++mt) {
        const int mi = mt ^ (kc & 1);
#pragma unroll
        for (int nt = 0; nt < 2; ++nt) {
            const int ni = nt ^ ((kc >> 1) & 1);
#pragma unroll
            for (int rg = 0; rg < 4; ++rg) {
                int p = mi * 16 + qd * 4 + rg;
                int c = ch * 128 + (wv << 5) + ni * 16 + r15;
                atomicAdd(&ob[p * C_ + c], acc[mi][ni][rg]);
            }
        }
    }
}

extern "C" void kernel_launch(void* const* d_in, const int* in_sizes, int n_in,
                              void* d_out, int out_size, void* d_ws, size_t ws_size,
                              hipStream_t stream) {
    const float* x      = (const float*)d_in[0];
    const float* part   = (const float*)d_in[1];
    const float* conv_w = (const float*)d_in[2];
    const float* conv_b = (const float*)d_in[3];
    float* att = (float*)d_ws;                    // 1.6 MB scratch

    // zero d_out (1 MB) for the atomic accumulation
    hipMemsetAsync(d_out, 0, (size_t)out_size * sizeof(float), stream);

    att_kernel<<<dim3((B_ * (HW_ / 4) + 63) / 64), dim3(64), 0, stream>>>(
        part, conv_w, conv_b, att);

    gemm_atomic<<<dim3(KSPLIT, B_, 2), dim3(256), 0, stream>>>(
        x, part, att, (float*)d_out);
}

// Round 6
// 178.226 us; speedup vs baseline: 1.0463x; 1.0450x over previous
//
#include <hip/hip_runtime.h>
#include <cstdint>

// Problem constants: B=32, C=256, P=32, H=W=56
#define B_    32
#define C_    256
#define P_    32
#define HW_   3136
#define NSTEP 98          // k-steps of 32 (98*32 = 3136)

typedef __attribute__((ext_vector_type(8))) short  short8;   // 8 x bf16 (MFMA A/B frag)
typedef __attribute__((ext_vector_type(4))) float  floatx4;  // MFMA C/D frag

__device__ __forceinline__ unsigned short f2bf(float f) {
    // round-to-nearest-even f32 -> bf16
    union { float f; unsigned u; } v; v.f = f;
    unsigned r = v.u + 0x7fffu + ((v.u >> 16) & 1u);
    return (unsigned short)(r >> 16);
}

// ---------------------------------------------------------------------------
// Kernel 1: wpart[b,p,hw] = bf16( part[b,p,hw] * sigmoid(sum_p' part*w + b) )
// Two passes over p per thread (2nd pass L1/L2-hot). Fully overwrites wpart.
// ---------------------------------------------------------------------------
__global__ __launch_bounds__(64) void wprep_kernel(
    const float* __restrict__ part, const float* __restrict__ conv_w,
    const float* __restrict__ conv_b, unsigned short* __restrict__ wpart)
{
    const int HW4 = HW_ / 4;                          // 784
    int i4 = blockIdx.x * 64 + threadIdx.x;           // over B*HW/4 = 25088
    if (i4 >= B_ * HW4) return;
    int b  = i4 / HW4;
    int hw = (i4 - b * HW4) * 4;

    const float* pb = part + (size_t)b * P_ * HW_ + hw;
    float bias = conv_b[0];
    float4 z = make_float4(bias, bias, bias, bias);
#pragma unroll
    for (int p = 0; p < P_; ++p) {
        float w = conv_w[p];
        float4 v = *(const float4*)(pb + (size_t)p * HW_);
        z.x += v.x * w; z.y += v.y * w; z.z += v.z * w; z.w += v.w * w;
    }
    float4 a;
    a.x = 1.0f / (1.0f + __expf(-z.x));
    a.y = 1.0f / (1.0f + __expf(-z.y));
    a.z = 1.0f / (1.0f + __expf(-z.z));
    a.w = 1.0f / (1.0f + __expf(-z.w));

    unsigned short* ob = wpart + (size_t)b * P_ * HW_ + hw;
#pragma unroll
    for (int p = 0; p < P_; ++p) {
        float4 v = *(const float4*)(pb + (size_t)p * HW_);   // L1/L2-hot reload
        ushort4 o;
        o.x = f2bf(v.x * a.x); o.y = f2bf(v.y * a.y);
        o.z = f2bf(v.z * a.z); o.w = f2bf(v.w * a.w);
        *(ushort4*)(ob + (size_t)p * HW_) = o;
    }
}

// ---------------------------------------------------------------------------
// Kernel 2: barrier-free streaming bf16-MFMA GEMM.
//   feats[b,p,c] = sum_k wpart[b,p,k] * x[b,c,k]
// Block = 512 thr (8 waves) covering (b, c-tile of 16). Wave w owns k-steps
// [w*98/8,(w+1)*98/8): per step it loads A-frags DIRECT from global wpart
// (b128, L2-hot) and B-frags DIRECT from global x (2x float4/lane, cvt to
// bf16 in regs) -> 2 MFMA. No LDS operands, NO barriers in the K-loop:
// each wave streams independently (fillBuffer-style MLP). Single end-of-
// kernel LDS reduction over the 8 waves, plain coalesced stores to d_out.
// ---------------------------------------------------------------------------
__global__ __launch_bounds__(512) void gemm_stream(
    const float* __restrict__ x,              // [B,C,HW] fp32
    const unsigned short* __restrict__ wpart, // [B,P,HW] bf16
    float* __restrict__ out)                  // [B, P*C]
{
    __shared__ float red[8][512];             // 16 KB

    const int ct = blockIdx.x;                // c-tile 0..15
    const int b  = blockIdx.y;                // batch
    const int c0 = ct * 16;

    const int tid  = threadIdx.x;
    const int wv   = tid >> 6;                // 0..7 : k-split slice
    const int lane = tid & 63;
    const int qd   = lane >> 4;               // quad 0..3 -> k-offset qd*8
    const int r15  = lane & 15;               // row within 16

    const int t0 = wv * NSTEP / 8;
    const int t1 = (wv + 1) * NSTEP / 8;

    // lane-fixed base pointers (k advances by 32 per step)
    const float*          xr = x     + (size_t)b * C_ * HW_ + (size_t)(c0 + r15) * HW_ + qd * 8;
    const unsigned short* ar = wpart + (size_t)b * P_ * HW_ + (size_t)r15 * HW_       + qd * 8;

    floatx4 acc0 = (floatx4)0.0f;   // m-tile 0 (p 0..15)
    floatx4 acc1 = (floatx4)0.0f;   // m-tile 1 (p 16..31)

#pragma unroll 4
    for (int t = t0; t < t1; ++t) {
        const int kb = t * 32;
        // A fragments: 16B contiguous per lane, 64B/row = full lines, L2-hot
        short8 a0 = *(const short8*)(ar + kb);
        short8 a1 = *(const short8*)(ar + (size_t)16 * HW_ + kb);
        // B fragment: 8 consecutive k floats of this lane's x row
        float4 xv0 = *(const float4*)(xr + kb);
        float4 xv1 = *(const float4*)(xr + kb + 4);
        short8 bf;
        bf[0] = (short)f2bf(xv0.x); bf[1] = (short)f2bf(xv0.y);
        bf[2] = (short)f2bf(xv0.z); bf[3] = (short)f2bf(xv0.w);
        bf[4] = (short)f2bf(xv1.x); bf[5] = (short)f2bf(xv1.y);
        bf[6] = (short)f2bf(xv1.z); bf[7] = (short)f2bf(xv1.w);

        acc0 = __builtin_amdgcn_mfma_f32_16x16x32_bf16(a0, bf, acc0, 0, 0, 0);
        acc1 = __builtin_amdgcn_mfma_f32_16x16x32_bf16(a1, bf, acc1, 0, 0, 0);
    }

    // ---- end-of-kernel reduction across the 8 k-split waves ----
    // D layout: m = qd*4 + rg (+16 for acc1), n = r15 ; local idx = m*16 + n
#pragma unroll
    for (int rg = 0; rg < 4; ++rg) {
        red[wv][(qd * 4 + rg) * 16 + r15]      = acc0[rg];
        red[wv][(16 + qd * 4 + rg) * 16 + r15] = acc1[rg];
    }
    __syncthreads();

    float s = 0.0f;
#pragma unroll
    for (int w = 0; w < 8; ++w) s += red[w][tid];

    // tid -> (p = tid>>4, cl = tid&15); 16 consecutive tids = 64B line
    out[(size_t)b * (P_ * C_) + (tid >> 4) * C_ + c0 + (tid & 15)] = s;
}

extern "C" void kernel_launch(void* const* d_in, const int* in_sizes, int n_in,
                              void* d_out, int out_size, void* d_ws, size_t ws_size,
                              hipStream_t stream) {
    const float* x      = (const float*)d_in[0];
    const float* part   = (const float*)d_in[1];
    const float* conv_w = (const float*)d_in[2];
    const float* conv_b = (const float*)d_in[3];
    unsigned short* wpart = (unsigned short*)d_ws;   // [B,P,HW] bf16 = 6.4 MB

    wprep_kernel<<<dim3((B_ * (HW_ / 4) + 63) / 64), dim3(64), 0, stream>>>(
        part, conv_w, conv_b, wpart);

    gemm_stream<<<dim3(16, B_), dim3(512), 0, stream>>>(
        x, wpart, (float*)d_out);
}

// Round 7
// 174.256 us; speedup vs baseline: 1.0701x; 1.0228x over previous
//
#include <hip/hip_runtime.h>
#include <cstdint>

// Problem constants: B=32, C=256, P=32, H=W=56
#define B_    32
#define C_    256
#define P_    32
#define HW_   3136
#define NSTEP 98          // k-steps of 32 (98*32 = 3136)

typedef __attribute__((ext_vector_type(8))) short  short8;   // 8 x bf16 (MFMA A/B frag)
typedef __attribute__((ext_vector_type(4))) float  floatx4;  // MFMA C/D frag

__device__ __forceinline__ unsigned short f2bf(float f) {
    // round-to-nearest-even f32 -> bf16
    union { float f; unsigned u; } v; v.f = f;
    unsigned r = v.u + 0x7fffu + ((v.u >> 16) & 1u);
    return (unsigned short)(r >> 16);
}

// ---------------------------------------------------------------------------
// Kernel 1: wpart[b,p,hw] = bf16( part[b,p,hw] * sigmoid(sum_p' part*w + b) )
// Two passes over p per thread (2nd pass L1/L2-hot). ~4 us.
// ---------------------------------------------------------------------------
__global__ __launch_bounds__(64) void wprep_kernel(
    const float* __restrict__ part, const float* __restrict__ conv_w,
    const float* __restrict__ conv_b, unsigned short* __restrict__ wpart)
{
    const int HW4 = HW_ / 4;                          // 784
    int i4 = blockIdx.x * 64 + threadIdx.x;           // over B*HW/4 = 25088
    if (i4 >= B_ * HW4) return;
    int b  = i4 / HW4;
    int hw = (i4 - b * HW4) * 4;

    const float* pb = part + (size_t)b * P_ * HW_ + hw;
    float bias = conv_b[0];
    float4 z = make_float4(bias, bias, bias, bias);
#pragma unroll
    for (int p = 0; p < P_; ++p) {
        float w = conv_w[p];
        float4 v = *(const float4*)(pb + (size_t)p * HW_);
        z.x += v.x * w; z.y += v.y * w; z.z += v.z * w; z.w += v.w * w;
    }
    float4 a;
    a.x = 1.0f / (1.0f + __expf(-z.x));
    a.y = 1.0f / (1.0f + __expf(-z.y));
    a.z = 1.0f / (1.0f + __expf(-z.z));
    a.w = 1.0f / (1.0f + __expf(-z.w));

    unsigned short* ob = wpart + (size_t)b * P_ * HW_ + hw;
#pragma unroll
    for (int p = 0; p < P_; ++p) {
        float4 v = *(const float4*)(pb + (size_t)p * HW_);   // L1/L2-hot reload
        ushort4 o;
        o.x = f2bf(v.x * a.x); o.y = f2bf(v.y * a.y);
        o.z = f2bf(v.z * a.z); o.w = f2bf(v.w * a.w);
        *(ushort4*)(ob + (size_t)p * HW_) = o;
    }
}

// ---------------------------------------------------------------------------
// Kernel 2: barrier-free streaming bf16-MFMA GEMM, v2.
//   feats[b,p,c] = sum_k wpart[b,p,k] * x[b,c,k]
// Grid = (8 c-chunks, 32 b) = 256 blocks x 512 thr -> 8 waves/CU, 1 blk/CU.
// Block covers c-32 x all-P.  Wave w owns k-slice [w*98/8,(w+1)*98/8):
// per step, A-frags direct from global wpart (2x b128, L3/L2-hot since only
// 8 blocks/b re-read it: 51 MB total vs R6's 102 MB) and B-frags direct from
// global x (4x float4/lane, cvt in regs) -> 4 MFMA. No barriers in K-loop.
// Epilogue: single LDS reduce over the 8 k-slice waves, plain stores.
// ---------------------------------------------------------------------------
__global__ __launch_bounds__(512, 2) void gemm_stream2(
    const float* __restrict__ x,              // [B,C,HW] fp32
    const unsigned short* __restrict__ wpart, // [B,P,HW] bf16
    float* __restrict__ out)                  // [B, P*C]
{
    __shared__ float red[8][1024];            // 32 KB

    const int ct = blockIdx.x;                // c-chunk 0..7
    const int b  = blockIdx.y;                // batch
    const int c0 = ct * 32;

    const int tid  = threadIdx.x;
    const int wv   = tid >> 6;                // 0..7 : k-slice
    const int lane = tid & 63;
    const int qd   = lane >> 4;               // quad 0..3 -> k-offset qd*8
    const int r15  = lane & 15;               // row within 16

    const int t0 = wv * NSTEP / 8;
    const int t1 = (wv + 1) * NSTEP / 8;

    // lane-fixed base pointers (k advances by 32 floats per step)
    const float*          xr0 = x + (size_t)b * C_ * HW_ + (size_t)(c0 + r15) * HW_ + qd * 8;
    const float*          xr1 = xr0 + (size_t)16 * HW_;
    const unsigned short* ar0 = wpart + (size_t)b * P_ * HW_ + (size_t)r15 * HW_ + qd * 8;
    const unsigned short* ar1 = ar0 + (size_t)16 * HW_;

    floatx4 acc[2][2];
#pragma unroll
    for (int a = 0; a < 2; ++a)
#pragma unroll
        for (int g = 0; g < 2; ++g) acc[a][g] = (floatx4)0.0f;

#pragma unroll 4
    for (int t = t0; t < t1; ++t) {
        const int kb = t * 32;
        // A fragments: 16B contiguous per lane, 64B/row full lines, L2/L3-hot
        short8 a0 = *(const short8*)(ar0 + kb);
        short8 a1 = *(const short8*)(ar1 + kb);
        // B fragments: 8 consecutive k floats of each of this lane's 2 x-rows
        float4 x00 = *(const float4*)(xr0 + kb);
        float4 x01 = *(const float4*)(xr0 + kb + 4);
        float4 x10 = *(const float4*)(xr1 + kb);
        float4 x11 = *(const float4*)(xr1 + kb + 4);
        short8 b0, b1;
        b0[0] = (short)f2bf(x00.x); b0[1] = (short)f2bf(x00.y);
        b0[2] = (short)f2bf(x00.z); b0[3] = (short)f2bf(x00.w);
        b0[4] = (short)f2bf(x01.x); b0[5] = (short)f2bf(x01.y);
        b0[6] = (short)f2bf(x01.z); b0[7] = (short)f2bf(x01.w);
        b1[0] = (short)f2bf(x10.x); b1[1] = (short)f2bf(x10.y);
        b1[2] = (short)f2bf(x10.z); b1[3] = (short)f2bf(x10.w);
        b1[4] = (short)f2bf(x11.x); b1[5] = (short)f2bf(x11.y);
        b1[6] = (short)f2bf(x11.z); b1[7] = (short)f2bf(x11.w);

        acc[0][0] = __builtin_amdgcn_mfma_f32_16x16x32_bf16(a0, b0, acc[0][0], 0, 0, 0);
        acc[0][1] = __builtin_amdgcn_mfma_f32_16x16x32_bf16(a0, b1, acc[0][1], 0, 0, 0);
        acc[1][0] = __builtin_amdgcn_mfma_f32_16x16x32_bf16(a1, b0, acc[1][0], 0, 0, 0);
        acc[1][1] = __builtin_amdgcn_mfma_f32_16x16x32_bf16(a1, b1, acc[1][1], 0, 0, 0);
    }

    // ---- reduction across the 8 k-slice waves ----
    // D layout: m = a*16 + qd*4 + rg, n = g*16 + r15 ; local idx = m*32 + n
#pragma unroll
    for (int a = 0; a < 2; ++a)
#pragma unroll
        for (int g = 0; g < 2; ++g)
#pragma unroll
            for (int rg = 0; rg < 4; ++rg)
                red[wv][(a * 16 + qd * 4 + rg) * 32 + g * 16 + r15] = acc[a][g][rg];
    __syncthreads();

#pragma unroll
    for (int h = 0; h < 2; ++h) {
        int idx = h * 512 + tid;              // 0..1023
        float s = 0.0f;
#pragma unroll
        for (int w = 0; w < 8; ++w) s += red[w][idx];
        int p  = idx >> 5;                    // 0..31
        int cl = idx & 31;                    // 0..31
        out[(size_t)b * (P_ * C_) + p * C_ + c0 + cl] = s;
    }
}

extern "C" void kernel_launch(void* const* d_in, const int* in_sizes, int n_in,
                              void* d_out, int out_size, void* d_ws, size_t ws_size,
                              hipStream_t stream) {
    const float* x      = (const float*)d_in[0];
    const float* part   = (const float*)d_in[1];
    const float* conv_w = (const float*)d_in[2];
    const float* conv_b = (const float*)d_in[3];
    unsigned short* wpart = (unsigned short*)d_ws;   // [B,P,HW] bf16 = 6.4 MB

    wprep_kernel<<<dim3((B_ * (HW_ / 4) + 63) / 64), dim3(64), 0, stream>>>(
        part, conv_w, conv_b, wpart);

    gemm_stream2<<<dim3(8, B_), dim3(512), 0, stream>>>(
        x, wpart, (float*)d_out);
}